// Round 3
// baseline (81.688 us; speedup 1.0000x reference)
//
#include <hip/hip_runtime.h>
#include <hip/hip_bf16.h>

#define KW    7
#define PADW  3
#define HW    56
#define ROWS  8
#define TILE_H (ROWS + KW - 1)   // 14
#define TILE_W 64                // 62 used, padded stride
#define NTHREADS 448             // 8 rows * 56 cols = 7 waves
#define NCHUNK 7                 // 56 / ROWS

__global__ __launch_bounds__(NTHREADS) void saconv_kernel(
    const float* __restrict__ x,
    const float* __restrict__ r,
    const float* __restrict__ Wq,
    const float* __restrict__ Wk,
    const float* __restrict__ Wv,
    const float* __restrict__ Wr,
    const float* __restrict__ up,
    const float* __restrict__ vp,
    float* __restrict__ out)
{
    __shared__ float xs[TILE_H][TILE_W];
    __shared__ float ro[KW * KW];

    const int tid   = threadIdx.x;
    const int bid   = blockIdx.x;
    const int chunk = bid % NCHUNK;
    const int g     = (bid / NCHUNK) & 63;
    const int b     = bid / (NCHUNK * 64);
    const int y0    = chunk * ROWS;

    // per-group scalars (uniform -> scalar loads)
    const float wq = Wq[g];
    const float wk = Wk[g];
    const float wv = Wv[g];
    const float ug = up[g];
    const float vg = vp[g];

    // r_o[g][pos] = sum_c r[(g*4+c), pos] * Wr[g*4+c]  (pos = i*7+j, row-major,
    // matching _windows' (i,j) flatten order)
    if (tid < KW * KW) {
        float acc = 0.f;
#pragma unroll
        for (int c = 0; c < 4; ++c) {
            acc += r[(g * 4 + c) * (KW * KW) + tid] * Wr[g * 4 + c];
        }
        ro[tid] = acc;
    }

    // stage padded tile: global rows [y0-3, y0+10], cols [-3, 58], zeros outside
    const float* xb = x + (size_t)(b * 64 + g) * (HW * HW);
    for (int idx = tid; idx < TILE_H * 62; idx += NTHREADS) {
        const int ty = idx / 62;
        const int tx = idx - ty * 62;
        const int gy = y0 - PADW + ty;
        const int gx = tx - PADW;
        float v = 0.f;
        if (gy >= 0 && gy < HW && gx >= 0 && gx < HW)
            v = xb[gy * HW + gx];
        xs[ty][tx] = v;
    }
    __syncthreads();

    const int row = tid / HW;        // 0..7
    const int col = tid - row * HW;  // 0..55

    const float xc = xs[row + PADW][col + PADW];
    const float q  = xc * wq;
    const float a  = (q + ug) * wk;
    const float cc = q + vg;

    // softmax over 49 taps, no max-subtraction (|logit| << 88, fp32 exp safe).
    // Padding taps stay in the softmax: xv=0 there, logit = cc*ro[pos] (matches ref).
    float se = 0.f, sx = 0.f;
#pragma unroll
    for (int i = 0; i < KW; ++i) {
#pragma unroll
        for (int j = 0; j < KW; ++j) {
            const float xv = xs[row + i][col + j];
            const float l  = a * xv + cc * ro[i * KW + j];
            const float e  = __expf(l);
            se += e;
            sx += e * xv;
        }
    }

    out[((size_t)(b * 64 + g) * HW + (y0 + row)) * HW + col] = wv * sx / se;
}

extern "C" void kernel_launch(void* const* d_in, const int* in_sizes, int n_in,
                              void* d_out, int out_size, void* d_ws, size_t ws_size,
                              hipStream_t stream) {
    const float* x  = (const float*)d_in[0];
    const float* r  = (const float*)d_in[1];
    const float* Wq = (const float*)d_in[2];
    const float* Wk = (const float*)d_in[3];
    const float* Wv = (const float*)d_in[4];
    const float* Wr = (const float*)d_in[5];
    const float* up = (const float*)d_in[6];
    const float* vp = (const float*)d_in[7];
    float* out = (float*)d_out;

    const int grid = 4 * 64 * NCHUNK;  // B * G * chunks = 1792
    saconv_kernel<<<grid, NTHREADS, 0, stream>>>(x, r, Wq, Wk, Wv, Wr, up, vp, out);
}

// Round 4
// 77.255 us; speedup vs baseline: 1.0574x; 1.0574x over previous
//
#include <hip/hip_runtime.h>
#include <hip/hip_bf16.h>

#define KW    7
#define PADW  3
#define HW    56
#define ROWS  8
#define TILE_H (ROWS + KW - 1)   // 14
#define TILE_W 64                // 62 used, padded stride
#define NTHREADS 448             // 8 rows * 56 cols = 7 waves
#define NCHUNK 7                 // 56 / ROWS

#define LOG2E 1.44269504088896340736f

__global__ __launch_bounds__(NTHREADS) void saconv_kernel(
    const float* __restrict__ x,
    const float* __restrict__ r,
    const float* __restrict__ Wq,
    const float* __restrict__ Wk,
    const float* __restrict__ Wv,
    const float* __restrict__ Wr,
    const float* __restrict__ up,
    const float* __restrict__ vp,
    float* __restrict__ out)
{
    __shared__ float xs[TILE_H][TILE_W];
    __shared__ float ro[KW * KW];

    const int tid   = threadIdx.x;
    const int bid   = blockIdx.x;
    const int chunk = bid % NCHUNK;
    const int g     = (bid / NCHUNK) & 63;
    const int b     = bid / (NCHUNK * 64);
    const int y0    = chunk * ROWS;

    // per-group scalars (uniform -> scalar loads)
    const float wq = Wq[g];
    const float wk = Wk[g];
    const float wv = Wv[g];
    const float ug = up[g];
    const float vg = vp[g];

    // r_o[g][pos] = sum_c r[(g*4+c), pos] * Wr[g*4+c]  (pos = i*7+j row-major,
    // matching _windows' (i,j) flatten order)
    if (tid < KW * KW) {
        float acc = 0.f;
#pragma unroll
        for (int c = 0; c < 4; ++c) {
            acc += r[(g * 4 + c) * (KW * KW) + tid] * Wr[g * 4 + c];
        }
        ro[tid] = acc;
    }

    // stage padded tile: global rows [y0-3, y0+10], cols [-3, 58], zeros outside
    const float* xb = x + (size_t)(b * 64 + g) * (HW * HW);
    for (int idx = tid; idx < TILE_H * 62; idx += NTHREADS) {
        const int ty = idx / 62;
        const int tx = idx - ty * 62;
        const int gy = y0 - PADW + ty;
        const int gx = tx - PADW;
        float v = 0.f;
        if (gy >= 0 && gy < HW && gx >= 0 && gx < HW)
            v = xb[gy * HW + gx];
        xs[ty][tx] = v;
    }
    __syncthreads();

    const int row = tid / HW;        // 0..7
    const int col = tid - row * HW;  // 0..55

    // exp(l) = exp2(l*log2e): fold log2e into the per-thread constants so the
    // inner loop is fma + v_exp_f32 + add + fma per tap (no extra mul).
    const float xc  = xs[row + PADW][col + PADW];
    const float q   = xc * wq;
    const float a2  = (q + ug) * wk * LOG2E;
    const float cc2 = (q + vg) * LOG2E;

    // softmax over 49 taps, no max-subtraction (|logit| << 126 in exp2 domain).
    // Padding taps stay in the softmax: xv=0 there, logit = cc*ro[pos] (matches ref).
    float se = 0.f, sx = 0.f;
#pragma unroll
    for (int i = 0; i < KW; ++i) {
#pragma unroll
        for (int j = 0; j < KW; ++j) {
            const float xv = xs[row + i][col + j];
            const float l2 = __builtin_fmaf(a2, xv, cc2 * ro[i * KW + j]);
            const float e  = __builtin_amdgcn_exp2f(l2);   // bare v_exp_f32
            se += e;
            sx = __builtin_fmaf(e, xv, sx);
        }
    }

    // v_rcp_f32 (~1 ulp) instead of the precise-division sequence.
    out[((size_t)(b * 64 + g) * HW + (y0 + row)) * HW + col] =
        wv * sx * __builtin_amdgcn_rcpf(se);
}

extern "C" void kernel_launch(void* const* d_in, const int* in_sizes, int n_in,
                              void* d_out, int out_size, void* d_ws, size_t ws_size,
                              hipStream_t stream) {
    const float* x  = (const float*)d_in[0];
    const float* r  = (const float*)d_in[1];
    const float* Wq = (const float*)d_in[2];
    const float* Wk = (const float*)d_in[3];
    const float* Wv = (const float*)d_in[4];
    const float* Wr = (const float*)d_in[5];
    const float* up = (const float*)d_in[6];
    const float* vp = (const float*)d_in[7];
    float* out = (float*)d_out;

    const int grid = 4 * 64 * NCHUNK;  // B * G * chunks = 1792
    saconv_kernel<<<grid, NTHREADS, 0, stream>>>(x, r, Wq, Wk, Wv, Wr, up, vp, out);
}